// Round 15
// baseline (2897.969 us; speedup 1.0000x reference)
//
#include <hip/hip_runtime.h>
#include <hip/hip_bf16.h>

#define TPB 256
constexpr int B_ = 256, S_ = 512, D_ = 512, Q_ = 256, NM_ = 512;
constexpr int NB = 64, NT = 8;

typedef _Float16 f16x8 __attribute__((ext_vector_type(8)));
typedef float f32x4 __attribute__((ext_vector_type(4)));

__device__ __forceinline__ int pidx(int j, int a){ return j*(15-j)/2 + (a-j-1); } // j<a, 28 tiles

// XCD-co-locating decode: x=bid&7 -> XCD; per XCD: tasks fastest, then cls, then group.
__device__ __forceinline__ void decode_mt(int bid, int W, int& m, int& t){
  int x = bid & 7, r = bid >> 3;
  t = r % W; int u = r / W;
  m = (((u >> 1)*8 + x) << 1) | (u & 1);
}

// direct row-major 64x64 stage into pitch-68 LDS (256 threads)
__device__ __forceinline__ void stage_D(const float* __restrict__ src, size_t ld,
                                        float (*dst)[68], int t)
{
  int r = t >> 2, seg = (t & 3) * 16;
  const float4* s4 = (const float4*)(src + (size_t)r*ld + seg);
  #pragma unroll
  for (int i=0;i<4;i++) *((float4*)&dst[r][seg + i*4]) = s4[i];
}

// acc[u][v] += sum_kk Aop[kk][tr*4+u] * Bop[kk][tc*4+v]
__device__ __forceinline__ void mm_acc68(const float (*Aop)[68], const float (*Bop)[68],
                                         float acc[4][4], int tr, int tc)
{
  for (int kk=0;kk<64;kk++){
    float4 av = *((const float4*)&Aop[kk][tr*4]);
    float4 bv = *((const float4*)&Bop[kk][tc*4]);
    float a[4]={av.x,av.y,av.z,av.w}, b2[4]={bv.x,bv.y,bv.z,bv.w};
    #pragma unroll
    for (int u=0;u<4;u++)
      #pragma unroll
      for (int v=0;v<4;v++) acc[u][v] = fmaf(a[u], b2[v], acc[u][v]);
  }
}

// ---------------- prep (fused stats): transpose X -> f16 hi/lo [B][D][S], masked;
// also computes mu (3 means), cnt, wpbits. One block per (b, d-tile), loops 8 s-tiles.
__global__ __launch_bounds__(TPB) void k_prep(const float* __restrict__ X,
                                              const int* __restrict__ labels,
                                              const int* __restrict__ slen,
                                              unsigned short* __restrict__ Xvh,
                                              unsigned short* __restrict__ Xvl,
                                              float* __restrict__ mu,
                                              float* __restrict__ cnt,
                                              unsigned int* __restrict__ wpbits)
{
  int b = blockIdx.y, dz = blockIdx.x;
  int d0 = dz*64;
  int t = threadIdx.x;
  __shared__ float Tl[64][65];
  __shared__ int lab[S_];
  __shared__ float red[TPB];
  int L = slen[b];
  for (int s = t; s < S_; s += TPB){
    int lb = labels[b*S_ + s];
    lab[s] = (s < L) ? lb : -1;
  }
  __syncthreads();
  if (dz == 0 && t < 16){
    unsigned int wword = 0;
    for (int i2=0;i2<32;i2++) if (lab[t*32+i2]==1) wword |= (1u<<i2);
    wpbits[b*16+t] = wword;
  }
  int cpi=0, cni=0;
  for (int s=t; s<S_; s+=TPB){ cpi += (lab[s]==1); cni += (lab[s]==0); }
  red[t] = (float)cpi; __syncthreads();
  for (int o=TPB/2;o>0;o>>=1){ if(t<o) red[t]+=red[t+o]; __syncthreads(); }
  float cp = red[0]; __syncthreads();
  red[t] = (float)cni; __syncthreads();
  for (int o=TPB/2;o>0;o>>=1){ if(t<o) red[t]+=red[t+o]; __syncthreads(); }
  float cn = red[0];
  if (dz==0 && t==0){ cnt[b*2+0]=cn; cnt[b*2+1]=cp; }
  __syncthreads();

  int dr = t>>2, sc = (t&3)*16;
  float accp = 0.f, accn = 0.f;
  for (int sz=0; sz<8; sz++){
    int s0 = sz*64;
    const float* src = X + ((size_t)b*S_ + s0)*D_ + d0;
    { int r = t>>2, seg = (t&3)*16;
      const float4* s4 = (const float4*)(src + (size_t)r*D_ + seg);
      #pragma unroll
      for (int i=0;i<4;i++){ float4 v = s4[i];
        Tl[seg+i*4+0][r]=v.x; Tl[seg+i*4+1][r]=v.y; Tl[seg+i*4+2][r]=v.z; Tl[seg+i*4+3][r]=v.w; } }
    __syncthreads();
    union U16 { unsigned short u[8]; uint4 v; };
    U16 H[2], Lo[2];
    #pragma unroll
    for (int g=0; g<2; g++)
      #pragma unroll
      for (int i=0;i<8;i++){
        int si = sc + g*8 + i;
        float x = (s0+si < L) ? Tl[dr][si] : 0.f;
        _Float16 hh = (_Float16)x;
        float lo = x - (float)hh;
        H[g].u[i]  = __builtin_bit_cast(unsigned short, hh);
        Lo[g].u[i] = __builtin_bit_cast(unsigned short, (_Float16)lo);
      }
    size_t o = ((size_t)b*D_ + d0+dr)*S_ + s0 + sc;
    *(uint4*)(Xvh+o)   = H[0].v;  *(uint4*)(Xvh+o+8) = H[1].v;
    *(uint4*)(Xvl+o)   = Lo[0].v; *(uint4*)(Xvl+o+8) = Lo[1].v;
    #pragma unroll
    for (int i=0;i<16;i++){
      int si = sc + i;
      int e = lab[s0+si];
      float x = Tl[dr][si];
      accp += (e==1) ? x : 0.f;
      accn += (e==0) ? x : 0.f;
    }
    __syncthreads();
  }
  accp += __shfl_xor(accp, 1, 64);
  accp += __shfl_xor(accp, 2, 64);
  accn += __shfl_xor(accn, 1, 64);
  accn += __shfl_xor(accn, 2, 64);
  if ((t&3)==0){
    int d = d0 + dr;
    float stv = (float)L;
    float* mb = mu + (size_t)b*3*D_;
    mb[0*D_ + d] = accn/cn;
    mb[1*D_ + d] = accp/cp;
    mb[2*D_ + d] = (accn+accp)/stv;
  }
}

// ---------------- MFMA Gram -> A matrices (upper 128-tiles incl. diagonal) ----------------
__global__ __launch_bounds__(TPB,2) void k_gram(const unsigned short* __restrict__ Xvh,
                                                const unsigned short* __restrict__ Xvl,
                                                const unsigned int* __restrict__ wpbits,
                                                const float* __restrict__ mu,
                                                const float* __restrict__ cnt,
                                                const int* __restrict__ slen,
                                                float* __restrict__ A)
{
  __shared__ unsigned short sAvh[128][32], sAvl[128][32], sAph[128][32], sApl[128][32],
                            sBvh[128][32], sBvl[128][32];
  int id = blockIdx.x;
  int g = id>>3;
  int b = (g/10)*8 + (id&7);
  int z = g%10;
  int ti=0; while (z >= 4-ti){ z -= 4-ti; ti++; } int tj = ti + z;
  int i0 = ti*128, j0 = tj*128;
  int t = threadIdx.x, lane = t&63, w = t>>6;
  int wr = w>>1, wc = w&1, l15 = lane&15;

  f32x4 acc_t[4][4], acc_p[4][4];
  f32x4 z4 = {0.f,0.f,0.f,0.f};
  #pragma unroll
  for (int mf=0;mf<4;mf++)
    #pragma unroll
    for (int nf=0;nf<4;nf++){ acc_t[mf][nf]=z4; acc_p[mf][nf]=z4; }

  const size_t baseA = ((size_t)b*D_ + i0)*S_;
  const size_t baseB = ((size_t)b*D_ + j0)*S_;
  int phx = (lane>>4) ^ ((l15>>1)&3);

  for (int ks=0; ks<16; ks++){
    int s0 = ks*32;
    unsigned int wpw = wpbits[b*16 + ks];
    __syncthreads();
    #pragma unroll
    for (int h=0; h<2; h++){
      int ci = t + h*256;
      int row = ci>>2, cpos = ci&3;
      int ph = cpos ^ ((row>>1)&3);
      size_t ga = baseA + (size_t)row*S_ + s0 + cpos*8;
      size_t gb = baseB + (size_t)row*S_ + s0 + cpos*8;
      uint4 vh = *(const uint4*)(Xvh+ga);
      uint4 vl = *(const uint4*)(Xvl+ga);
      uint4 bh = *(const uint4*)(Xvh+gb);
      uint4 bl = *(const uint4*)(Xvl+gb);
      unsigned int m8 = (wpw >> (cpos*8)) & 0xFFu;
      uint4 mk;
      mk.x = ((m8&1u)?0xFFFFu:0u)  | ((m8&2u)?0xFFFF0000u:0u);
      mk.y = ((m8&4u)?0xFFFFu:0u)  | ((m8&8u)?0xFFFF0000u:0u);
      mk.z = ((m8&16u)?0xFFFFu:0u) | ((m8&32u)?0xFFFF0000u:0u);
      mk.w = ((m8&64u)?0xFFFFu:0u) | ((m8&128u)?0xFFFF0000u:0u);
      uint4 p4, q4;
      p4.x = vh.x&mk.x; p4.y = vh.y&mk.y; p4.z = vh.z&mk.z; p4.w = vh.w&mk.w;
      q4.x = vl.x&mk.x; q4.y = vl.y&mk.y; q4.z = vl.z&mk.z; q4.w = vl.w&mk.w;
      *(uint4*)&sAvh[row][ph*8] = vh;
      *(uint4*)&sAvl[row][ph*8] = vl;
      *(uint4*)&sAph[row][ph*8] = p4;
      *(uint4*)&sApl[row][ph*8] = q4;
      *(uint4*)&sBvh[row][ph*8] = bh;
      *(uint4*)&sBvl[row][ph*8] = bl;
    }
    __syncthreads();
    f16x8 Avh[4], Avl[4], Aph[4], Apl[4];
    #pragma unroll
    for (int mf=0;mf<4;mf++){
      int r = wr*64 + mf*16 + l15;
      Avh[mf] = __builtin_bit_cast(f16x8, *(const uint4*)&sAvh[r][phx*8]);
      Avl[mf] = __builtin_bit_cast(f16x8, *(const uint4*)&sAvl[r][phx*8]);
      Aph[mf] = __builtin_bit_cast(f16x8, *(const uint4*)&sAph[r][phx*8]);
      Apl[mf] = __builtin_bit_cast(f16x8, *(const uint4*)&sApl[r][phx*8]);
    }
    #pragma unroll
    for (int nf=0;nf<4;nf++){
      int r = wc*64 + nf*16 + l15;
      f16x8 Bh = __builtin_bit_cast(f16x8, *(const uint4*)&sBvh[r][phx*8]);
      f16x8 Bl = __builtin_bit_cast(f16x8, *(const uint4*)&sBvl[r][phx*8]);
      #pragma unroll
      for (int mf=0;mf<4;mf++){
        acc_t[mf][nf] = __builtin_amdgcn_mfma_f32_16x16x32_f16(Avh[mf], Bh, acc_t[mf][nf],0,0,0);
        acc_t[mf][nf] = __builtin_amdgcn_mfma_f32_16x16x32_f16(Avh[mf], Bl, acc_t[mf][nf],0,0,0);
        acc_t[mf][nf] = __builtin_amdgcn_mfma_f32_16x16x32_f16(Avl[mf], Bh, acc_t[mf][nf],0,0,0);
        acc_p[mf][nf] = __builtin_amdgcn_mfma_f32_16x16x32_f16(Aph[mf], Bh, acc_p[mf][nf],0,0,0);
        acc_p[mf][nf] = __builtin_amdgcn_mfma_f32_16x16x32_f16(Aph[mf], Bl, acc_p[mf][nf],0,0,0);
        acc_p[mf][nf] = __builtin_amdgcn_mfma_f32_16x16x32_f16(Apl[mf], Bh, acc_p[mf][nf],0,0,0);
      }
    }
  }
  float cn = cnt[b*2+0], cp = cnt[b*2+1];
  float stv = (float)slen[b];
  float kn = 0.1f/(cn-1.f), kp = 0.1f/(cp-1.f), kt = 0.9f/(stv-1.f);
  float rn = 0.1f*cn/(cn-1.f), rp = 0.1f*cp/(cp-1.f), rt = 0.9f*stv/(stv-1.f);
  const float* mb = mu + (size_t)b*3*D_;
  float* A0 = A + (size_t)(b*2+0)*D_*D_;
  float* A1 = A + (size_t)(b*2+1)*D_*D_;
  int rbase = i0 + wr*64 + (lane>>4)*4;
  int cbase = j0 + wc*64 + l15;
  #pragma unroll
  for (int mf=0;mf<4;mf++){
    #pragma unroll
    for (int i=0;i<4;i++){
      int r = rbase + mf*16 + i;
      float mnr = mb[r], mpr = mb[D_+r], mtr = mb[2*D_+r];
      #pragma unroll
      for (int nf=0;nf<4;nf++){
        int c = cbase + nf*16;
        float mnc = mb[c], mpc = mb[D_+c], mtc = mb[2*D_+c];
        float gp = acc_p[mf][nf][i];
        float gt = acc_t[mf][nf][i];
        float gn = gt - gp;
        float diag = (r==c)?0.1f:0.f;
        A0[(size_t)r*D_ + c] = kn*gn + kt*gt - rn*mnr*mnc - rt*mtr*mtc + diag;
        A1[(size_t)r*D_ + c] = kp*gp + kt*gt - rp*mpr*mpc - rt*mtr*mtc + diag;
      }
    }
  }
}

// ---------------- diag block Cholesky + triangular inverse (transposed out) ----------------
__global__ __launch_bounds__(TPB) void k_diag(float* __restrict__ A,
                                              float* __restrict__ invDT, int j)
{
  int m, t0; decode_mt(blockIdx.x, 1, m, t0); (void)t0;
  int t = threadIdx.x;
  __shared__ float Ld[64][65];
  __shared__ float Iv[64][65];
  float* Ab = A + (size_t)m*D_*D_ + (size_t)(j*NB)*D_ + j*NB;
  for (int l=t; l<4096; l+=TPB){ int r=l>>6, c=l&63; Ld[r][c] = Ab[(size_t)r*D_ + c]; Iv[r][c] = 0.f; }
  __syncthreads();
  for (int k=0;k<64;k++){
    if (t==0) Ld[k][k] = sqrtf(Ld[k][k]);
    __syncthreads();
    if (t>k && t<64) Ld[t][k] /= Ld[k][k];
    __syncthreads();
    for (int l=t; l<4096; l+=TPB){
      int r=l>>6, c=l&63;
      if (r>k && c>k) Ld[r][c] = fmaf(-Ld[r][k], Ld[c][k], Ld[r][c]);
    }
    __syncthreads();
  }
  if (t < 64){
    int c = t;
    Iv[c][c] = 1.f/Ld[c][c];
    for (int r=c+1;r<64;r++){
      float s = 0.f;
      for (int k2=c;k2<r;k2++) s += Ld[r][k2]*Iv[k2][c];
      Iv[r][c] = -s/Ld[r][r];
    }
  }
  __syncthreads();
  float* Ib = invDT + ((size_t)m*8 + j)*4096;
  for (int l=t; l<4096; l+=TPB){ Ib[l] = Iv[l&63][l>>6]; }
}

// ---------------- panel: upper(j,ib) <- invD * upper(j,ib); emit f16T hi/lo ----------------
__global__ __launch_bounds__(TPB) void k_panel(float* __restrict__ A,
                                               const float* __restrict__ invDT,
                                               unsigned short* __restrict__ Ut,
                                               int j, int W)
{
  int m, ti; decode_mt(blockIdx.x, W, m, ti);
  int ib = j + 1 + ti;
  int t = threadIdx.x, tr = t&15, tc = t>>4;
  __shared__ float Ta[64][68], Tb[64][68];
  float* U = A + (size_t)m*D_*D_ + (size_t)(j*NB)*D_ + ib*NB;
  stage_D(invDT + ((size_t)m*8 + j)*4096, 64, Ta, t);
  stage_D(U, D_, Tb, t);
  __syncthreads();
  float acc[4][4] = {};
  mm_acc68(Ta, Tb, acc, tr, tc);
  #pragma unroll
  for (int u=0;u<4;u++){
    float4 o = make_float4(acc[u][0],acc[u][1],acc[u][2],acc[u][3]);
    *((float4*)(U + (size_t)(tr*4+u)*D_ + tc*4)) = o;
  }
  __syncthreads();
  unsigned short* shh = (unsigned short*)Ta;
  unsigned short* shl = (unsigned short*)Tb;
  #pragma unroll
  for (int u=0;u<4;u++)
    #pragma unroll
    for (int v=0;v<4;v++){
      float val = acc[u][v];                  // P[x=tr*4+u][y=tc*4+v]
      _Float16 h = (_Float16)val;
      float lo = val - (float)h;
      shh[(tc*4+v)*72 + tr*4+u] = __builtin_bit_cast(unsigned short, h);
      shl[(tc*4+v)*72 + tr*4+u] = __builtin_bit_cast(unsigned short, (_Float16)lo);
    }
  __syncthreads();
  unsigned short* Ub = Ut + ((size_t)m*28 + pidx(j, ib)) * 8192;
  { int r = t>>2, cs = (t&3)*16;
    *(uint4*)(Ub + r*64 + cs)          = *(uint4*)&shh[r*72 + cs];
    *(uint4*)(Ub + r*64 + cs + 8)      = *(uint4*)&shh[r*72 + cs + 8];
    *(uint4*)(Ub + 4096 + r*64 + cs)   = *(uint4*)&shl[r*72 + cs];
    *(uint4*)(Ub + 4096 + r*64 + cs+8) = *(uint4*)&shl[r*72 + cs + 8];
  }
}

// ---------------- MFMA trail helpers ----------------
__device__ __forceinline__ void trail_stage(const unsigned short* __restrict__ Ua,
                                            const unsigned short* __restrict__ Ub,
                                            unsigned short (*Ah)[72], unsigned short (*Al)[72],
                                            unsigned short (*Bh)[72], unsigned short (*Bl)[72],
                                            int t)
{
  int r = t>>2, cs = (t&3)*16;
  *(uint4*)&Ah[r][cs]   = *(const uint4*)(Ua + r*64 + cs);
  *(uint4*)&Ah[r][cs+8] = *(const uint4*)(Ua + r*64 + cs + 8);
  *(uint4*)&Al[r][cs]   = *(const uint4*)(Ua + 4096 + r*64 + cs);
  *(uint4*)&Al[r][cs+8] = *(const uint4*)(Ua + 4096 + r*64 + cs + 8);
  *(uint4*)&Bh[r][cs]   = *(const uint4*)(Ub + r*64 + cs);
  *(uint4*)&Bh[r][cs+8] = *(const uint4*)(Ub + r*64 + cs + 8);
  *(uint4*)&Bl[r][cs]   = *(const uint4*)(Ub + 4096 + r*64 + cs);
  *(uint4*)&Bl[r][cs+8] = *(const uint4*)(Ub + 4096 + r*64 + cs + 8);
}

__device__ __forceinline__ void trail_mfma(const unsigned short (*Ah)[72], const unsigned short (*Al)[72],
                                           const unsigned short (*Bh)[72], const unsigned short (*Bl)[72],
                                           f32x4 acc[4], int w, int l15, int lk)
{
  #pragma unroll
  for (int s=0;s<2;s++){
    f16x8 Afh = __builtin_bit_cast(f16x8, *(const uint4*)&Ah[w*16 + l15][s*32 + lk*8]);
    f16x8 Afl = __builtin_bit_cast(f16x8, *(const uint4*)&Al[w*16 + l15][s*32 + lk*8]);
    #pragma unroll
    for (int ni=0;ni<4;ni++){
      f16x8 Bfh = __builtin_bit_cast(f16x8, *(const uint4*)&Bh[ni*16 + l15][s*32 + lk*8]);
      f16x8 Bfl = __builtin_bit_cast(f16x8, *(const uint4*)&Bl[ni*16 + l15][s*32 + lk*8]);
      acc[ni] = __builtin_amdgcn_mfma_f32_16x16x32_f16(Afh, Bfh, acc[ni],0,0,0);
      acc[ni] = __builtin_amdgcn_mfma_f32_16x16x32_f16(Afh, Bfl, acc[ni],0,0,0);
      acc[ni] = __builtin_amdgcn_mfma_f32_16x16x32_f16(Afl, Bfh, acc[ni],0,0,0);
    }
  }
}

__device__ __forceinline__ void trail_rmw(float* __restrict__ Cb, const f32x4 acc[4],
                                          int w, int l15, int lk)
{
  #pragma unroll
  for (int ni=0;ni<4;ni++)
    #pragma unroll
    for (int i=0;i<4;i++){
      int r = w*16 + lk*4 + i, cc = ni*16 + l15;
      float* pC = Cb + (size_t)r*D_ + cc;
      *pC -= acc[ni][i];
    }
}

// ---------------- trailrow (MFMA): upper(row,b) -= U(j,row)^T U(j,b) ----------------
__global__ __launch_bounds__(TPB) void k_trailrow(float* __restrict__ A,
                                                  const unsigned short* __restrict__ Ut,
                                                  int j, int row, int W)
{
  int m, z; decode_mt(blockIdx.x, W, m, z);
  int b2 = row + z;
  int t = threadIdx.x, lane = t&63, w = t>>6, l15 = lane&15, lk = lane>>4;
  __shared__ unsigned short Ah[64][72], Al[64][72], Bh[64][72], Bl[64][72];
  const unsigned short* Um = Ut + (size_t)m*28*8192;
  trail_stage(Um + (size_t)pidx(j,row)*8192, Um + (size_t)pidx(j,b2)*8192, Ah, Al, Bh, Bl, t);
  __syncthreads();
  f32x4 acc[4];
  #pragma unroll
  for (int ni=0;ni<4;ni++) acc[ni] = (f32x4){0.f,0.f,0.f,0.f};
  trail_mfma(Ah, Al, Bh, Bl, acc, w, l15, lk);
  float* Cb = A + (size_t)m*D_*D_ + (size_t)(row*NB)*D_ + b2*NB;
  trail_rmw(Cb, acc, w, l15, lk);
}

// ---------------- trail2 (MFMA): upper(a,b) -= cols jb,jb+1 ----------------
__global__ __launch_bounds__(TPB) void k_trail2(float* __restrict__ A,
                                                const unsigned short* __restrict__ Ut,
                                                int jb, int W)
{
  int m, z; decode_mt(blockIdx.x, W, m, z);
  int base = jb + 2;
  int Tn = NT - base;
  int p = 0, zz = z;
  while (zz >= Tn - p){ zz -= Tn - p; p++; }
  int a2 = base + p, b2 = a2 + zz;
  int t = threadIdx.x, lane = t&63, w = t>>6, l15 = lane&15, lk = lane>>4;
  __shared__ unsigned short Ah[64][72], Al[64][72], Bh[64][72], Bl[64][72];
  const unsigned short* Um = Ut + (size_t)m*28*8192;
  f32x4 acc[4];
  #pragma unroll
  for (int ni=0;ni<4;ni++) acc[ni] = (f32x4){0.f,0.f,0.f,0.f};
  #pragma unroll
  for (int c=0;c<2;c++){
    int j = jb + c;
    __syncthreads();
    trail_stage(Um + (size_t)pidx(j,a2)*8192, Um + (size_t)pidx(j,b2)*8192, Ah, Al, Bh, Bl, t);
    __syncthreads();
    trail_mfma(Ah, Al, Bh, Bl, acc, w, l15, lk);
  }
  float* Cb = A + (size_t)m*D_*D_ + (size_t)(a2*NB)*D_ + b2*NB;
  trail_rmw(Cb, acc, w, l15, lk);
}

// ---------------- fused rform + forward solve + maha + logits (T14 prefetch, race-fixed) ----------------
__global__ __launch_bounds__(TPB) void k_solvefin(const float* __restrict__ Qs,
                                                  const float* __restrict__ mu,
                                                  const float* __restrict__ A,
                                                  const float* __restrict__ invDT,
                                                  float* __restrict__ Z,
                                                  const int* __restrict__ qlen,
                                                  const float* __restrict__ lps,
                                                  float* __restrict__ out)
{
  int m, t0; decode_mt(blockIdx.x, 4, m, t0);
  int q0 = t0*NB;
  int b = m>>1, cls = m&1;
  int t = threadIdx.x, tr = t&15, tc = t>>4;
  int pr = t>>2, pseg = (t&3)*16;
  __shared__ float Ta[64][68], Tb[64][68];
  const float* Am = A + (size_t)m*D_*D_;
  float* Zm = Z + (size_t)m*D_*Q_;
  const float* muv = mu + ((size_t)b*3 + cls)*D_;
  float cs[4] = {0.f,0.f,0.f,0.f};
  for (int j=0;j<NT;j++){
    float acc[4][4];
    {
      float4 mv = *(const float4*)&muv[j*NB + tr*4];
      #pragma unroll
      for (int v=0;v<4;v++){
        float4 qv = *(const float4*)&Qs[((size_t)b*Q_ + q0 + tc*4 + v)*D_ + j*NB + tr*4];
        acc[0][v] = mv.x - qv.x;
        acc[1][v] = mv.y - qv.y;
        acc[2][v] = mv.z - qv.z;
        acc[3][v] = mv.w - qv.w;
      }
    }
    // RACE FIX: order previous j's Z global writes (by other threads) before this
    // j's prefetch reads of those Z rows.
    __syncthreads();
    // prefetch first tile pair (or invD when j==0) into registers
    float4 rA[4], rZ[4];
    if (j > 0){
      const float* Ls = Am + (size_t)(0*NB)*D_ + j*NB;
      const float* Zs = Zm + (size_t)(0*NB + pr)*Q_ + q0 + pseg;
      #pragma unroll
      for (int i=0;i<4;i++) rA[i] = *(const float4*)(Ls + (size_t)pr*D_ + pseg + i*4);
      #pragma unroll
      for (int i=0;i<4;i++) rZ[i] = *(const float4*)(Zs + i*4);
    } else {
      const float* Is = invDT + ((size_t)m*8 + j)*4096;
      #pragma unroll
      for (int i=0;i<4;i++) rA[i] = *(const float4*)(Is + (size_t)pr*64 + pseg + i*4);
    }
    for (int k=0;k<j;k++){
      __syncthreads();                      // prior readers of Ta/Tb done
      #pragma unroll
      for (int i=0;i<4;i++) *((float4*)&Ta[pr][pseg + i*4]) = rA[i];
      #pragma unroll
      for (int i=0;i<4;i++) *((float4*)&Tb[pr][pseg + i*4]) = rZ[i];
      // prefetch next tile pair (or invD on last iter) while mm runs
      if (k+1 < j){
        const float* Ls = Am + (size_t)((k+1)*NB)*D_ + j*NB;
        const float* Zs = Zm + (size_t)((k+1)*NB + pr)*Q_ + q0 + pseg;
        #pragma unroll
        for (int i=0;i<4;i++) rA[i] = *(const float4*)(Ls + (size_t)pr*D_ + pseg + i*4);
        #pragma unroll
        for (int i=0;i<4;i++) rZ[i] = *(const float4*)(Zs + i*4);
      } else {
        const float* Is = invDT + ((size_t)m*8 + j)*4096;
        #pragma unroll
        for (int i=0;i<4;i++) rA[i] = *(const float4*)(Is + (size_t)pr*64 + pseg + i*4);
      }
      __syncthreads();
      for (int kk=0;kk<64;kk++){
        float4 av = *((const float4*)&Ta[kk][tr*4]);
        float4 bv = *((const float4*)&Tb[kk][tc*4]);
        float a[4]={av.x,av.y,av.z,av.w}, bb2[4]={bv.x,bv.y,bv.z,bv.w};
        #pragma unroll
        for (int u=0;u<4;u++)
          #pragma unroll
          for (int v=0;v<4;v++) acc[u][v] = fmaf(-a[u], bb2[v], acc[u][v]);
      }
    }
    __syncthreads();                        // mm readers done; safe to overwrite Ta/Tb
    // S -> Tb with XOR granule swizzle; invD (prefetched in rA) -> Ta
    #pragma unroll
    for (int u=0;u<4;u++){
      int cb = (tc*4) ^ ((tr&7)<<2);
      *((float4*)&Tb[tr*4+u][cb]) = make_float4(acc[u][0],acc[u][1],acc[u][2],acc[u][3]);
    }
    #pragma unroll
    for (int i=0;i<4;i++) *((float4*)&Ta[pr][pseg + i*4]) = rA[i];
    __syncthreads();
    float o4[4][4] = {};
    for (int kk=0;kk<64;kk++){
      float4 av = *((const float4*)&Ta[kk][tr*4]);
      float4 bv = *((const float4*)&Tb[kk][(tc*4) ^ (((kk>>2)&7)<<2)]);
      float a[4]={av.x,av.y,av.z,av.w}, bb2[4]={bv.x,bv.y,bv.z,bv.w};
      #pragma unroll
      for (int u=0;u<4;u++)
        #pragma unroll
        for (int v=0;v<4;v++) o4[u][v] = fmaf(a[u], bb2[v], o4[u][v]);
    }
    if (j < NT-1){
      #pragma unroll
      for (int u=0;u<4;u++){
        float4 o = make_float4(o4[u][0], o4[u][1], o4[u][2], o4[u][3]);
        *((float4*)(Zm + (size_t)(j*NB + tr*4+u)*Q_ + q0 + tc*4)) = o;
      }
    }
    #pragma unroll
    for (int u=0;u<4;u++)
      #pragma unroll
      for (int v=0;v<4;v++) cs[v] = fmaf(o4[u][v], o4[u][v], cs[v]);
  }
  __syncthreads();
  float* red = &Ta[0][0];
  #pragma unroll
  for (int v=0;v<4;v++) red[(tc*4+v)*16 + tr] = cs[v];
  __syncthreads();
  if (t < 64){
    float s = 0.f;
    #pragma unroll
    for (int i=0;i<16;i++) s += red[t*16 + i];
    int q = q0 + t;
    float valid = (q < qlen[b]) ? 1.f : 0.f;
    float s2 = expf(2.f*lps[0]);
    out[((size_t)b*Q_ + q)*2 + cls] = -s2*s*valid;
  }
}

extern "C" void kernel_launch(void* const* d_in, const int* in_sizes, int n_in,
                              void* d_out, int out_size, void* d_ws, size_t ws_size,
                              hipStream_t stream) {
  (void)in_sizes; (void)n_in; (void)out_size;
  const float* X   = (const float*)d_in[0];
  const int*   lab = (const int*)d_in[1];
  const float* Qs  = (const float*)d_in[2];
  const int*   sl  = (const int*)d_in[3];
  const int*   ql  = (const int*)d_in[4];
  const float* lps = (const float*)d_in[5];
  float* out = (float*)d_out;

  float* A  = (float*)d_ws;                          // [512,512,512] f32
  float* Z  = A + (size_t)NM_*D_*D_;                 // [512,512,256] f32
  unsigned short* Xvh = (unsigned short*)Z;          // overlays Z (gram phase only)
  unsigned short* Xvl = Xvh + (size_t)B_*D_*S_;
  unsigned short* Ut  = (unsigned short*)Z;          // overlays Z (chol phase only): [512][28][8192]
  float* invDT = Z + (size_t)NM_*D_*Q_;              // [512,8,64,64] f32 (transposed)
  float* mu   = invDT + (size_t)NM_*8*64*64;         // [256,3,512]
  float* cnt  = mu + (size_t)B_*3*D_;                // [256,2]
  unsigned int* wpbits = (unsigned int*)(cnt + B_*2);// [256,16]
  size_t need = (size_t)((char*)(wpbits + B_*16) - (char*)d_ws);
  if (ws_size < need) return;

  k_prep<<<dim3(8, B_), dim3(TPB), 0, stream>>>(X, lab, sl, Xvh, Xvl, mu, cnt, wpbits);
  k_gram<<<dim3(2560), dim3(TPB), 0, stream>>>(Xvh, Xvl, wpbits, mu, cnt, sl, A);

  // lazy two-column Cholesky with MFMA trail (f16T panels live in the Z region)
  for (int j=0; j<NT; j+=2){
    k_diag<<<dim3(NM_), dim3(TPB), 0, stream>>>(A, invDT, j);
    int nb0 = NT-1-j;
    if (nb0 > 0){
      k_panel<<<dim3(NM_*nb0), dim3(TPB), 0, stream>>>(A, invDT, Ut, j, nb0);
      int wr = NT - (j+1);
      k_trailrow<<<dim3(NM_*wr), dim3(TPB), 0, stream>>>(A, Ut, j, j+1, wr);
      k_diag<<<dim3(NM_), dim3(TPB), 0, stream>>>(A, invDT, j+1);
      int nb1 = NT-1-(j+1);
      if (nb1 > 0){
        k_panel<<<dim3(NM_*nb1), dim3(TPB), 0, stream>>>(A, invDT, Ut, j+1, nb1);
        int Tn = NT - (j+2);
        int np = Tn*(Tn+1)/2;
        if (np > 0) k_trail2<<<dim3(NM_*np), dim3(TPB), 0, stream>>>(A, Ut, j, np);
      }
    }
  }

  k_solvefin<<<dim3(NM_*4), dim3(TPB), 0, stream>>>(Qs, mu, A, invDT, Z, ql, lps, out);
}

// Round 16
// 2421.585 us; speedup vs baseline: 1.1967x; 1.1967x over previous
//
#include <hip/hip_runtime.h>
#include <hip/hip_bf16.h>

#define TPB 256
constexpr int B_ = 256, S_ = 512, D_ = 512, Q_ = 256, NM_ = 512;
constexpr int NB = 64, NT = 8;

typedef _Float16 f16x8 __attribute__((ext_vector_type(8)));
typedef float f32x4 __attribute__((ext_vector_type(4)));

__device__ __forceinline__ int pidx(int j, int a){ return j*(15-j)/2 + (a-j-1); } // j<a, 28 tiles

// XCD-co-locating decode: x=bid&7 -> XCD; per XCD: tasks fastest, then cls, then group.
__device__ __forceinline__ void decode_mt(int bid, int W, int& m, int& t){
  int x = bid & 7, r = bid >> 3;
  t = r % W; int u = r / W;
  m = (((u >> 1)*8 + x) << 1) | (u & 1);
}

// direct row-major 64x64 stage into pitch-68 LDS (256 threads)
__device__ __forceinline__ void stage_D(const float* __restrict__ src, size_t ld,
                                        float (*dst)[68], int t)
{
  int r = t >> 2, seg = (t & 3) * 16;
  const float4* s4 = (const float4*)(src + (size_t)r*ld + seg);
  #pragma unroll
  for (int i=0;i<4;i++) *((float4*)&dst[r][seg + i*4]) = s4[i];
}

// acc[u][v] += sum_kk Aop[kk][tr*4+u] * Bop[kk][tc*4+v]
__device__ __forceinline__ void mm_acc68(const float (*Aop)[68], const float (*Bop)[68],
                                         float acc[4][4], int tr, int tc)
{
  for (int kk=0;kk<64;kk++){
    float4 av = *((const float4*)&Aop[kk][tr*4]);
    float4 bv = *((const float4*)&Bop[kk][tc*4]);
    float a[4]={av.x,av.y,av.z,av.w}, b2[4]={bv.x,bv.y,bv.z,bv.w};
    #pragma unroll
    for (int u=0;u<4;u++)
      #pragma unroll
      for (int v=0;v<4;v++) acc[u][v] = fmaf(a[u], b2[v], acc[u][v]);
  }
}

// ---------------- prep (fused stats): transpose X -> f16 hi/lo [B][D][S], masked;
// also computes mu (3 means), cnt, wpbits. One block per (b, d-tile), loops 8 s-tiles.
__global__ __launch_bounds__(TPB) void k_prep(const float* __restrict__ X,
                                              const int* __restrict__ labels,
                                              const int* __restrict__ slen,
                                              unsigned short* __restrict__ Xvh,
                                              unsigned short* __restrict__ Xvl,
                                              float* __restrict__ mu,
                                              float* __restrict__ cnt,
                                              unsigned int* __restrict__ wpbits)
{
  int b = blockIdx.y, dz = blockIdx.x;
  int d0 = dz*64;
  int t = threadIdx.x;
  __shared__ float Tl[64][65];
  __shared__ int lab[S_];
  __shared__ float red[TPB];
  int L = slen[b];
  for (int s = t; s < S_; s += TPB){
    int lb = labels[b*S_ + s];
    lab[s] = (s < L) ? lb : -1;
  }
  __syncthreads();
  if (dz == 0 && t < 16){
    unsigned int wword = 0;
    for (int i2=0;i2<32;i2++) if (lab[t*32+i2]==1) wword |= (1u<<i2);
    wpbits[b*16+t] = wword;
  }
  int cpi=0, cni=0;
  for (int s=t; s<S_; s+=TPB){ cpi += (lab[s]==1); cni += (lab[s]==0); }
  red[t] = (float)cpi; __syncthreads();
  for (int o=TPB/2;o>0;o>>=1){ if(t<o) red[t]+=red[t+o]; __syncthreads(); }
  float cp = red[0]; __syncthreads();
  red[t] = (float)cni; __syncthreads();
  for (int o=TPB/2;o>0;o>>=1){ if(t<o) red[t]+=red[t+o]; __syncthreads(); }
  float cn = red[0];
  if (dz==0 && t==0){ cnt[b*2+0]=cn; cnt[b*2+1]=cp; }
  __syncthreads();

  int dr = t>>2, sc = (t&3)*16;
  float accp = 0.f, accn = 0.f;
  for (int sz=0; sz<8; sz++){
    int s0 = sz*64;
    const float* src = X + ((size_t)b*S_ + s0)*D_ + d0;
    { int r = t>>2, seg = (t&3)*16;
      const float4* s4 = (const float4*)(src + (size_t)r*D_ + seg);
      #pragma unroll
      for (int i=0;i<4;i++){ float4 v = s4[i];
        Tl[seg+i*4+0][r]=v.x; Tl[seg+i*4+1][r]=v.y; Tl[seg+i*4+2][r]=v.z; Tl[seg+i*4+3][r]=v.w; } }
    __syncthreads();
    union U16 { unsigned short u[8]; uint4 v; };
    U16 H[2], Lo[2];
    #pragma unroll
    for (int g=0; g<2; g++)
      #pragma unroll
      for (int i=0;i<8;i++){
        int si = sc + g*8 + i;
        float x = (s0+si < L) ? Tl[dr][si] : 0.f;
        _Float16 hh = (_Float16)x;
        float lo = x - (float)hh;
        H[g].u[i]  = __builtin_bit_cast(unsigned short, hh);
        Lo[g].u[i] = __builtin_bit_cast(unsigned short, (_Float16)lo);
      }
    size_t o = ((size_t)b*D_ + d0+dr)*S_ + s0 + sc;
    *(uint4*)(Xvh+o)   = H[0].v;  *(uint4*)(Xvh+o+8) = H[1].v;
    *(uint4*)(Xvl+o)   = Lo[0].v; *(uint4*)(Xvl+o+8) = Lo[1].v;
    #pragma unroll
    for (int i=0;i<16;i++){
      int si = sc + i;
      int e = lab[s0+si];
      float x = Tl[dr][si];
      accp += (e==1) ? x : 0.f;
      accn += (e==0) ? x : 0.f;
    }
    __syncthreads();
  }
  accp += __shfl_xor(accp, 1, 64);
  accp += __shfl_xor(accp, 2, 64);
  accn += __shfl_xor(accn, 1, 64);
  accn += __shfl_xor(accn, 2, 64);
  if ((t&3)==0){
    int d = d0 + dr;
    float stv = (float)L;
    float* mb = mu + (size_t)b*3*D_;
    mb[0*D_ + d] = accn/cn;
    mb[1*D_ + d] = accp/cp;
    mb[2*D_ + d] = (accn+accp)/stv;
  }
}

// ---------------- MFMA Gram -> A matrices (upper 128-tiles incl. diagonal) ----------------
__global__ __launch_bounds__(TPB,2) void k_gram(const unsigned short* __restrict__ Xvh,
                                                const unsigned short* __restrict__ Xvl,
                                                const unsigned int* __restrict__ wpbits,
                                                const float* __restrict__ mu,
                                                const float* __restrict__ cnt,
                                                const int* __restrict__ slen,
                                                float* __restrict__ A)
{
  __shared__ unsigned short sAvh[128][32], sAvl[128][32], sAph[128][32], sApl[128][32],
                            sBvh[128][32], sBvl[128][32];
  int id = blockIdx.x;
  int g = id>>3;
  int b = (g/10)*8 + (id&7);
  int z = g%10;
  int ti=0; while (z >= 4-ti){ z -= 4-ti; ti++; } int tj = ti + z;
  int i0 = ti*128, j0 = tj*128;
  int t = threadIdx.x, lane = t&63, w = t>>6;
  int wr = w>>1, wc = w&1, l15 = lane&15;

  f32x4 acc_t[4][4], acc_p[4][4];
  f32x4 z4 = {0.f,0.f,0.f,0.f};
  #pragma unroll
  for (int mf=0;mf<4;mf++)
    #pragma unroll
    for (int nf=0;nf<4;nf++){ acc_t[mf][nf]=z4; acc_p[mf][nf]=z4; }

  const size_t baseA = ((size_t)b*D_ + i0)*S_;
  const size_t baseB = ((size_t)b*D_ + j0)*S_;
  int phx = (lane>>4) ^ ((l15>>1)&3);

  for (int ks=0; ks<16; ks++){
    int s0 = ks*32;
    unsigned int wpw = wpbits[b*16 + ks];
    __syncthreads();
    #pragma unroll
    for (int h=0; h<2; h++){
      int ci = t + h*256;
      int row = ci>>2, cpos = ci&3;
      int ph = cpos ^ ((row>>1)&3);
      size_t ga = baseA + (size_t)row*S_ + s0 + cpos*8;
      size_t gb = baseB + (size_t)row*S_ + s0 + cpos*8;
      uint4 vh = *(const uint4*)(Xvh+ga);
      uint4 vl = *(const uint4*)(Xvl+ga);
      uint4 bh = *(const uint4*)(Xvh+gb);
      uint4 bl = *(const uint4*)(Xvl+gb);
      unsigned int m8 = (wpw >> (cpos*8)) & 0xFFu;
      uint4 mk;
      mk.x = ((m8&1u)?0xFFFFu:0u)  | ((m8&2u)?0xFFFF0000u:0u);
      mk.y = ((m8&4u)?0xFFFFu:0u)  | ((m8&8u)?0xFFFF0000u:0u);
      mk.z = ((m8&16u)?0xFFFFu:0u) | ((m8&32u)?0xFFFF0000u:0u);
      mk.w = ((m8&64u)?0xFFFFu:0u) | ((m8&128u)?0xFFFF0000u:0u);
      uint4 p4, q4;
      p4.x = vh.x&mk.x; p4.y = vh.y&mk.y; p4.z = vh.z&mk.z; p4.w = vh.w&mk.w;
      q4.x = vl.x&mk.x; q4.y = vl.y&mk.y; q4.z = vl.z&mk.z; q4.w = vl.w&mk.w;
      *(uint4*)&sAvh[row][ph*8] = vh;
      *(uint4*)&sAvl[row][ph*8] = vl;
      *(uint4*)&sAph[row][ph*8] = p4;
      *(uint4*)&sApl[row][ph*8] = q4;
      *(uint4*)&sBvh[row][ph*8] = bh;
      *(uint4*)&sBvl[row][ph*8] = bl;
    }
    __syncthreads();
    f16x8 Avh[4], Avl[4], Aph[4], Apl[4];
    #pragma unroll
    for (int mf=0;mf<4;mf++){
      int r = wr*64 + mf*16 + l15;
      Avh[mf] = __builtin_bit_cast(f16x8, *(const uint4*)&sAvh[r][phx*8]);
      Avl[mf] = __builtin_bit_cast(f16x8, *(const uint4*)&sAvl[r][phx*8]);
      Aph[mf] = __builtin_bit_cast(f16x8, *(const uint4*)&sAph[r][phx*8]);
      Apl[mf] = __builtin_bit_cast(f16x8, *(const uint4*)&sApl[r][phx*8]);
    }
    #pragma unroll
    for (int nf=0;nf<4;nf++){
      int r = wc*64 + nf*16 + l15;
      f16x8 Bh = __builtin_bit_cast(f16x8, *(const uint4*)&sBvh[r][phx*8]);
      f16x8 Bl = __builtin_bit_cast(f16x8, *(const uint4*)&sBvl[r][phx*8]);
      #pragma unroll
      for (int mf=0;mf<4;mf++){
        acc_t[mf][nf] = __builtin_amdgcn_mfma_f32_16x16x32_f16(Avh[mf], Bh, acc_t[mf][nf],0,0,0);
        acc_t[mf][nf] = __builtin_amdgcn_mfma_f32_16x16x32_f16(Avh[mf], Bl, acc_t[mf][nf],0,0,0);
        acc_t[mf][nf] = __builtin_amdgcn_mfma_f32_16x16x32_f16(Avl[mf], Bh, acc_t[mf][nf],0,0,0);
        acc_p[mf][nf] = __builtin_amdgcn_mfma_f32_16x16x32_f16(Aph[mf], Bh, acc_p[mf][nf],0,0,0);
        acc_p[mf][nf] = __builtin_amdgcn_mfma_f32_16x16x32_f16(Aph[mf], Bl, acc_p[mf][nf],0,0,0);
        acc_p[mf][nf] = __builtin_amdgcn_mfma_f32_16x16x32_f16(Apl[mf], Bh, acc_p[mf][nf],0,0,0);
      }
    }
  }
  float cn = cnt[b*2+0], cp = cnt[b*2+1];
  float stv = (float)slen[b];
  float kn = 0.1f/(cn-1.f), kp = 0.1f/(cp-1.f), kt = 0.9f/(stv-1.f);
  float rn = 0.1f*cn/(cn-1.f), rp = 0.1f*cp/(cp-1.f), rt = 0.9f*stv/(stv-1.f);
  const float* mb = mu + (size_t)b*3*D_;
  float* A0 = A + (size_t)(b*2+0)*D_*D_;
  float* A1 = A + (size_t)(b*2+1)*D_*D_;
  int rbase = i0 + wr*64 + (lane>>4)*4;
  int cbase = j0 + wc*64 + l15;
  #pragma unroll
  for (int mf=0;mf<4;mf++){
    #pragma unroll
    for (int i=0;i<4;i++){
      int r = rbase + mf*16 + i;
      float mnr = mb[r], mpr = mb[D_+r], mtr = mb[2*D_+r];
      #pragma unroll
      for (int nf=0;nf<4;nf++){
        int c = cbase + nf*16;
        float mnc = mb[c], mpc = mb[D_+c], mtc = mb[2*D_+c];
        float gp = acc_p[mf][nf][i];
        float gt = acc_t[mf][nf][i];
        float gn = gt - gp;
        float diag = (r==c)?0.1f:0.f;
        A0[(size_t)r*D_ + c] = kn*gn + kt*gt - rn*mnr*mnc - rt*mtr*mtc + diag;
        A1[(size_t)r*D_ + c] = kp*gp + kt*gt - rp*mpr*mpc - rt*mtr*mtc + diag;
      }
    }
  }
}

// ---------------- diag block Cholesky + triangular inverse (transposed out) ----------------
__global__ __launch_bounds__(TPB) void k_diag(float* __restrict__ A,
                                              float* __restrict__ invDT, int j)
{
  int m, t0; decode_mt(blockIdx.x, 1, m, t0); (void)t0;
  int t = threadIdx.x;
  __shared__ float Ld[64][65];
  __shared__ float Iv[64][65];
  float* Ab = A + (size_t)m*D_*D_ + (size_t)(j*NB)*D_ + j*NB;
  for (int l=t; l<4096; l+=TPB){ int r=l>>6, c=l&63; Ld[r][c] = Ab[(size_t)r*D_ + c]; Iv[r][c] = 0.f; }
  __syncthreads();
  for (int k=0;k<64;k++){
    if (t==0) Ld[k][k] = sqrtf(Ld[k][k]);
    __syncthreads();
    if (t>k && t<64) Ld[t][k] /= Ld[k][k];
    __syncthreads();
    for (int l=t; l<4096; l+=TPB){
      int r=l>>6, c=l&63;
      if (r>k && c>k) Ld[r][c] = fmaf(-Ld[r][k], Ld[c][k], Ld[r][c]);
    }
    __syncthreads();
  }
  if (t < 64){
    int c = t;
    Iv[c][c] = 1.f/Ld[c][c];
    for (int r=c+1;r<64;r++){
      float s = 0.f;
      for (int k2=c;k2<r;k2++) s += Ld[r][k2]*Iv[k2][c];
      Iv[r][c] = -s/Ld[r][r];
    }
  }
  __syncthreads();
  float* Ib = invDT + ((size_t)m*8 + j)*4096;
  for (int l=t; l<4096; l+=TPB){ Ib[l] = Iv[l&63][l>>6]; }
}

// ---------------- panel: upper(j,ib) <- invD * upper(j,ib); emit f16T hi/lo ----------------
__global__ __launch_bounds__(TPB) void k_panel(float* __restrict__ A,
                                               const float* __restrict__ invDT,
                                               unsigned short* __restrict__ Ut,
                                               int j, int W)
{
  int m, ti; decode_mt(blockIdx.x, W, m, ti);
  int ib = j + 1 + ti;
  int t = threadIdx.x, tr = t&15, tc = t>>4;
  __shared__ float Ta[64][68], Tb[64][68];
  float* U = A + (size_t)m*D_*D_ + (size_t)(j*NB)*D_ + ib*NB;
  stage_D(invDT + ((size_t)m*8 + j)*4096, 64, Ta, t);
  stage_D(U, D_, Tb, t);
  __syncthreads();
  float acc[4][4] = {};
  mm_acc68(Ta, Tb, acc, tr, tc);
  #pragma unroll
  for (int u=0;u<4;u++){
    float4 o = make_float4(acc[u][0],acc[u][1],acc[u][2],acc[u][3]);
    *((float4*)(U + (size_t)(tr*4+u)*D_ + tc*4)) = o;
  }
  __syncthreads();
  unsigned short* shh = (unsigned short*)Ta;
  unsigned short* shl = (unsigned short*)Tb;
  #pragma unroll
  for (int u=0;u<4;u++)
    #pragma unroll
    for (int v=0;v<4;v++){
      float val = acc[u][v];                  // P[x=tr*4+u][y=tc*4+v]
      _Float16 h = (_Float16)val;
      float lo = val - (float)h;
      shh[(tc*4+v)*72 + tr*4+u] = __builtin_bit_cast(unsigned short, h);
      shl[(tc*4+v)*72 + tr*4+u] = __builtin_bit_cast(unsigned short, (_Float16)lo);
    }
  __syncthreads();
  unsigned short* Ub = Ut + ((size_t)m*28 + pidx(j, ib)) * 8192;
  { int r = t>>2, cs = (t&3)*16;
    *(uint4*)(Ub + r*64 + cs)          = *(uint4*)&shh[r*72 + cs];
    *(uint4*)(Ub + r*64 + cs + 8)      = *(uint4*)&shh[r*72 + cs + 8];
    *(uint4*)(Ub + 4096 + r*64 + cs)   = *(uint4*)&shl[r*72 + cs];
    *(uint4*)(Ub + 4096 + r*64 + cs+8) = *(uint4*)&shl[r*72 + cs + 8];
  }
}

// ---------------- MFMA trail helpers ----------------
__device__ __forceinline__ void trail_stage(const unsigned short* __restrict__ Ua,
                                            const unsigned short* __restrict__ Ub,
                                            unsigned short (*Ah)[72], unsigned short (*Al)[72],
                                            unsigned short (*Bh)[72], unsigned short (*Bl)[72],
                                            int t)
{
  int r = t>>2, cs = (t&3)*16;
  *(uint4*)&Ah[r][cs]   = *(const uint4*)(Ua + r*64 + cs);
  *(uint4*)&Ah[r][cs+8] = *(const uint4*)(Ua + r*64 + cs + 8);
  *(uint4*)&Al[r][cs]   = *(const uint4*)(Ua + 4096 + r*64 + cs);
  *(uint4*)&Al[r][cs+8] = *(const uint4*)(Ua + 4096 + r*64 + cs + 8);
  *(uint4*)&Bh[r][cs]   = *(const uint4*)(Ub + r*64 + cs);
  *(uint4*)&Bh[r][cs+8] = *(const uint4*)(Ub + r*64 + cs + 8);
  *(uint4*)&Bl[r][cs]   = *(const uint4*)(Ub + 4096 + r*64 + cs);
  *(uint4*)&Bl[r][cs+8] = *(const uint4*)(Ub + 4096 + r*64 + cs + 8);
}

__device__ __forceinline__ void trail_mfma(const unsigned short (*Ah)[72], const unsigned short (*Al)[72],
                                           const unsigned short (*Bh)[72], const unsigned short (*Bl)[72],
                                           f32x4 acc[4], int w, int l15, int lk)
{
  #pragma unroll
  for (int s=0;s<2;s++){
    f16x8 Afh = __builtin_bit_cast(f16x8, *(const uint4*)&Ah[w*16 + l15][s*32 + lk*8]);
    f16x8 Afl = __builtin_bit_cast(f16x8, *(const uint4*)&Al[w*16 + l15][s*32 + lk*8]);
    #pragma unroll
    for (int ni=0;ni<4;ni++){
      f16x8 Bfh = __builtin_bit_cast(f16x8, *(const uint4*)&Bh[ni*16 + l15][s*32 + lk*8]);
      f16x8 Bfl = __builtin_bit_cast(f16x8, *(const uint4*)&Bl[ni*16 + l15][s*32 + lk*8]);
      acc[ni] = __builtin_amdgcn_mfma_f32_16x16x32_f16(Afh, Bfh, acc[ni],0,0,0);
      acc[ni] = __builtin_amdgcn_mfma_f32_16x16x32_f16(Afh, Bfl, acc[ni],0,0,0);
      acc[ni] = __builtin_amdgcn_mfma_f32_16x16x32_f16(Afl, Bfh, acc[ni],0,0,0);
    }
  }
}

__device__ __forceinline__ void trail_rmw(float* __restrict__ Cb, const f32x4 acc[4],
                                          int w, int l15, int lk)
{
  #pragma unroll
  for (int ni=0;ni<4;ni++)
    #pragma unroll
    for (int i=0;i<4;i++){
      int r = w*16 + lk*4 + i, cc = ni*16 + l15;
      float* pC = Cb + (size_t)r*D_ + cc;
      *pC -= acc[ni][i];
    }
}

// ---------------- trailrow (MFMA): upper(row,b) -= U(j,row)^T U(j,b) ----------------
__global__ __launch_bounds__(TPB) void k_trailrow(float* __restrict__ A,
                                                  const unsigned short* __restrict__ Ut,
                                                  int j, int row, int W)
{
  int m, z; decode_mt(blockIdx.x, W, m, z);
  int b2 = row + z;
  int t = threadIdx.x, lane = t&63, w = t>>6, l15 = lane&15, lk = lane>>4;
  __shared__ unsigned short Ah[64][72], Al[64][72], Bh[64][72], Bl[64][72];
  const unsigned short* Um = Ut + (size_t)m*28*8192;
  trail_stage(Um + (size_t)pidx(j,row)*8192, Um + (size_t)pidx(j,b2)*8192, Ah, Al, Bh, Bl, t);
  __syncthreads();
  f32x4 acc[4];
  #pragma unroll
  for (int ni=0;ni<4;ni++) acc[ni] = (f32x4){0.f,0.f,0.f,0.f};
  trail_mfma(Ah, Al, Bh, Bl, acc, w, l15, lk);
  float* Cb = A + (size_t)m*D_*D_ + (size_t)(row*NB)*D_ + b2*NB;
  trail_rmw(Cb, acc, w, l15, lk);
}

// ---------------- trail2 (MFMA): upper(a,b) -= cols jb,jb+1 ----------------
__global__ __launch_bounds__(TPB) void k_trail2(float* __restrict__ A,
                                                const unsigned short* __restrict__ Ut,
                                                int jb, int W)
{
  int m, z; decode_mt(blockIdx.x, W, m, z);
  int base = jb + 2;
  int Tn = NT - base;
  int p = 0, zz = z;
  while (zz >= Tn - p){ zz -= Tn - p; p++; }
  int a2 = base + p, b2 = a2 + zz;
  int t = threadIdx.x, lane = t&63, w = t>>6, l15 = lane&15, lk = lane>>4;
  __shared__ unsigned short Ah[64][72], Al[64][72], Bh[64][72], Bl[64][72];
  const unsigned short* Um = Ut + (size_t)m*28*8192;
  f32x4 acc[4];
  #pragma unroll
  for (int ni=0;ni<4;ni++) acc[ni] = (f32x4){0.f,0.f,0.f,0.f};
  #pragma unroll
  for (int c=0;c<2;c++){
    int j = jb + c;
    __syncthreads();
    trail_stage(Um + (size_t)pidx(j,a2)*8192, Um + (size_t)pidx(j,b2)*8192, Ah, Al, Bh, Bl, t);
    __syncthreads();
    trail_mfma(Ah, Al, Bh, Bl, acc, w, l15, lk);
  }
  float* Cb = A + (size_t)m*D_*D_ + (size_t)(a2*NB)*D_ + b2*NB;
  trail_rmw(Cb, acc, w, l15, lk);
}

// ---------------- fused rform + forward solve + maha + logits (T14, spill-proof) ----------------
#define LD16(r0,r1,r2,r3,base) { const float4* p4_ = (const float4*)(base); \
  r0 = p4_[0]; r1 = p4_[1]; r2 = p4_[2]; r3 = p4_[3]; }
#define ST16(dst,r0,r1,r2,r3) { float4* d4_ = (float4*)(dst); \
  d4_[0] = r0; d4_[1] = r1; d4_[2] = r2; d4_[3] = r3; }

__global__ __launch_bounds__(TPB) void k_solvefin(const float* __restrict__ Qs,
                                                  const float* __restrict__ mu,
                                                  const float* __restrict__ A,
                                                  const float* __restrict__ invDT,
                                                  float* __restrict__ Z,
                                                  const int* __restrict__ qlen,
                                                  const float* __restrict__ lps,
                                                  float* __restrict__ out)
{
  int m, t0; decode_mt(blockIdx.x, 4, m, t0);
  int q0 = t0*NB;
  int b = m>>1, cls = m&1;
  int t = threadIdx.x, tr = t&15, tc = t>>4;
  int pr = t>>2, pseg = (t&3)*16;
  __shared__ float Ta[64][68], Tb[64][68];
  const float* Am = A + (size_t)m*D_*D_;
  float* Zm = Z + (size_t)m*D_*Q_;
  const float* muv = mu + ((size_t)b*3 + cls)*D_;
  const float* Ivm = invDT + (size_t)m*8*4096;
  float cs[4] = {0.f,0.f,0.f,0.f};
  float4 rA0, rA1, rA2, rA3, rZ0, rZ1, rZ2, rZ3;
  for (int j=0;j<NT;j++){
    float acc[4][4];
    {
      float4 mv = *(const float4*)&muv[j*NB + tr*4];
      #pragma unroll
      for (int v=0;v<4;v++){
        float4 qv = *(const float4*)&Qs[((size_t)b*Q_ + q0 + tc*4 + v)*D_ + j*NB + tr*4];
        acc[0][v] = mv.x - qv.x;
        acc[1][v] = mv.y - qv.y;
        acc[2][v] = mv.z - qv.z;
        acc[3][v] = mv.w - qv.w;
      }
    }
    // order previous j's Z writes (other threads) before prefetch reads
    __syncthreads();
    if (j > 0){
      LD16(rA0,rA1,rA2,rA3, Am + (size_t)pr*D_ + j*NB + pseg);
      LD16(rZ0,rZ1,rZ2,rZ3, Zm + (size_t)pr*Q_ + q0 + pseg);
    } else {
      LD16(rA0,rA1,rA2,rA3, Ivm + (size_t)pr*64 + pseg);
    }
    for (int k=0;k<j;k++){
      __syncthreads();                      // prior readers of Ta/Tb done
      ST16(&Ta[pr][pseg], rA0,rA1,rA2,rA3);
      ST16(&Tb[pr][pseg], rZ0,rZ1,rZ2,rZ3);
      // prefetch next tile pair (or invD on last iter) while mm runs
      if (k+1 < j){
        LD16(rA0,rA1,rA2,rA3, Am + (size_t)((k+1)*NB + pr)*D_ + j*NB + pseg);
        LD16(rZ0,rZ1,rZ2,rZ3, Zm + (size_t)((k+1)*NB + pr)*Q_ + q0 + pseg);
      } else {
        LD16(rA0,rA1,rA2,rA3, Ivm + (size_t)(j*4096) + pr*64 + pseg);
      }
      __syncthreads();
      for (int kk=0;kk<64;kk++){
        float4 av = *((const float4*)&Ta[kk][tr*4]);
        float4 bv = *((const float4*)&Tb[kk][tc*4]);
        float a[4]={av.x,av.y,av.z,av.w}, bb2[4]={bv.x,bv.y,bv.z,bv.w};
        #pragma unroll
        for (int u=0;u<4;u++)
          #pragma unroll
          for (int v=0;v<4;v++) acc[u][v] = fmaf(-a[u], bb2[v], acc[u][v]);
      }
    }
    __syncthreads();                        // mm readers done; safe to overwrite Ta/Tb
    // S -> Tb with XOR granule swizzle; invD (prefetched) -> Ta
    #pragma unroll
    for (int u=0;u<4;u++){
      int cb = (tc*4) ^ ((tr&7)<<2);
      *((float4*)&Tb[tr*4+u][cb]) = make_float4(acc[u][0],acc[u][1],acc[u][2],acc[u][3]);
    }
    ST16(&Ta[pr][pseg], rA0,rA1,rA2,rA3);
    __syncthreads();
    float o4[4][4] = {};
    for (int kk=0;kk<64;kk++){
      float4 av = *((const float4*)&Ta[kk][tr*4]);
      float4 bv = *((const float4*)&Tb[kk][(tc*4) ^ (((kk>>2)&7)<<2)]);
      float a[4]={av.x,av.y,av.z,av.w}, bb2[4]={bv.x,bv.y,bv.z,bv.w};
      #pragma unroll
      for (int u=0;u<4;u++)
        #pragma unroll
        for (int v=0;v<4;v++) o4[u][v] = fmaf(a[u], bb2[v], o4[u][v]);
    }
    if (j < NT-1){
      #pragma unroll
      for (int u=0;u<4;u++){
        float4 o = make_float4(o4[u][0], o4[u][1], o4[u][2], o4[u][3]);
        *((float4*)(Zm + (size_t)(j*NB + tr*4+u)*Q_ + q0 + tc*4)) = o;
      }
    }
    #pragma unroll
    for (int u=0;u<4;u++)
      #pragma unroll
      for (int v=0;v<4;v++) cs[v] = fmaf(o4[u][v], o4[u][v], cs[v]);
  }
  __syncthreads();
  float* red = &Ta[0][0];
  #pragma unroll
  for (int v=0;v<4;v++) red[(tc*4+v)*16 + tr] = cs[v];
  __syncthreads();
  if (t < 64){
    float s = 0.f;
    #pragma unroll
    for (int i=0;i<16;i++) s += red[t*16 + i];
    int q = q0 + t;
    float valid = (q < qlen[b]) ? 1.f : 0.f;
    float s2 = expf(2.f*lps[0]);
    out[((size_t)b*Q_ + q)*2 + cls] = -s2*s*valid;
  }
}

extern "C" void kernel_launch(void* const* d_in, const int* in_sizes, int n_in,
                              void* d_out, int out_size, void* d_ws, size_t ws_size,
                              hipStream_t stream) {
  (void)in_sizes; (void)n_in; (void)out_size;
  const float* X   = (const float*)d_in[0];
  const int*   lab = (const int*)d_in[1];
  const float* Qs  = (const float*)d_in[2];
  const int*   sl  = (const int*)d_in[3];
  const int*   ql  = (const int*)d_in[4];
  const float* lps = (const float*)d_in[5];
  float* out = (float*)d_out;

  float* A  = (float*)d_ws;                          // [512,512,512] f32
  float* Z  = A + (size_t)NM_*D_*D_;                 // [512,512,256] f32
  unsigned short* Xvh = (unsigned short*)Z;          // overlays Z (gram phase only)
  unsigned short* Xvl = Xvh + (size_t)B_*D_*S_;
  unsigned short* Ut  = (unsigned short*)Z;          // overlays Z (chol phase only): [512][28][8192]
  float* invDT = Z + (size_t)NM_*D_*Q_;              // [512,8,64,64] f32 (transposed)
  float* mu   = invDT + (size_t)NM_*8*64*64;         // [256,3,512]
  float* cnt  = mu + (size_t)B_*3*D_;                // [256,2]
  unsigned int* wpbits = (unsigned int*)(cnt + B_*2);// [256,16]
  size_t need = (size_t)((char*)(wpbits + B_*16) - (char*)d_ws);
  if (ws_size < need) return;

  k_prep<<<dim3(8, B_), dim3(TPB), 0, stream>>>(X, lab, sl, Xvh, Xvl, mu, cnt, wpbits);
  k_gram<<<dim3(2560), dim3(TPB), 0, stream>>>(Xvh, Xvl, wpbits, mu, cnt, sl, A);

  // lazy two-column Cholesky with MFMA trail (f16T panels live in the Z region)
  for (int j=0; j<NT; j+=2){
    k_diag<<<dim3(NM_), dim3(TPB), 0, stream>>>(A, invDT, j);
    int nb0 = NT-1-j;
    if (nb0 > 0){
      k_panel<<<dim3(NM_*nb0), dim3(TPB), 0, stream>>>(A, invDT, Ut, j, nb0);
      int wr = NT - (j+1);
      k_trailrow<<<dim3(NM_*wr), dim3(TPB), 0, stream>>>(A, Ut, j, j+1, wr);
      k_diag<<<dim3(NM_), dim3(TPB), 0, stream>>>(A, invDT, j+1);
      int nb1 = NT-1-(j+1);
      if (nb1 > 0){
        k_panel<<<dim3(NM_*nb1), dim3(TPB), 0, stream>>>(A, invDT, Ut, j+1, nb1);
        int Tn = NT - (j+2);
        int np = Tn*(Tn+1)/2;
        if (np > 0) k_trail2<<<dim3(NM_*np), dim3(TPB), 0, stream>>>(A, Ut, j, np);
      }
    }
  }

  k_solvefin<<<dim3(NM_*4), dim3(TPB), 0, stream>>>(Qs, mu, A, invDT, Z, ql, lps, out);
}

// Round 17
// 2391.940 us; speedup vs baseline: 1.2116x; 1.0124x over previous
//
#include <hip/hip_runtime.h>
#include <hip/hip_bf16.h>

#define TPB 256
constexpr int B_ = 256, S_ = 512, D_ = 512, Q_ = 256, NM_ = 512;
constexpr int NB = 64, NT = 8;

typedef _Float16 f16x8 __attribute__((ext_vector_type(8)));
typedef float f32x4 __attribute__((ext_vector_type(4)));

__device__ __forceinline__ int pidx(int j, int a){ return j*(15-j)/2 + (a-j-1); } // j<a, 28 tiles

// XCD-co-locating decode: x=bid&7 -> XCD; per XCD: tasks fastest, then cls, then group.
__device__ __forceinline__ void decode_mt(int bid, int W, int& m, int& t){
  int x = bid & 7, r = bid >> 3;
  t = r % W; int u = r / W;
  m = (((u >> 1)*8 + x) << 1) | (u & 1);
}

// direct row-major 64x64 stage into pitch-68 LDS (256 threads)
__device__ __forceinline__ void stage_D(const float* __restrict__ src, size_t ld,
                                        float (*dst)[68], int t)
{
  int r = t >> 2, seg = (t & 3) * 16;
  const float4* s4 = (const float4*)(src + (size_t)r*ld + seg);
  #pragma unroll
  for (int i=0;i<4;i++) *((float4*)&dst[r][seg + i*4]) = s4[i];
}

// acc[u][v] += sum_kk Aop[kk][tr*4+u] * Bop[kk][tc*4+v]
__device__ __forceinline__ void mm_acc68(const float (*Aop)[68], const float (*Bop)[68],
                                         float acc[4][4], int tr, int tc)
{
  for (int kk=0;kk<64;kk++){
    float4 av = *((const float4*)&Aop[kk][tr*4]);
    float4 bv = *((const float4*)&Bop[kk][tc*4]);
    float a[4]={av.x,av.y,av.z,av.w}, b2[4]={bv.x,bv.y,bv.z,bv.w};
    #pragma unroll
    for (int u=0;u<4;u++)
      #pragma unroll
      for (int v=0;v<4;v++) acc[u][v] = fmaf(a[u], b2[v], acc[u][v]);
  }
}

// ---------------- prep (fused stats): transpose X -> f16 hi/lo [B][D][S], masked;
// also computes mu (3 means), cnt, wpbits. One block per (b, d-tile), loops 8 s-tiles.
__global__ __launch_bounds__(TPB) void k_prep(const float* __restrict__ X,
                                              const int* __restrict__ labels,
                                              const int* __restrict__ slen,
                                              unsigned short* __restrict__ Xvh,
                                              unsigned short* __restrict__ Xvl,
                                              float* __restrict__ mu,
                                              float* __restrict__ cnt,
                                              unsigned int* __restrict__ wpbits)
{
  int b = blockIdx.y, dz = blockIdx.x;
  int d0 = dz*64;
  int t = threadIdx.x;
  __shared__ float Tl[64][65];
  __shared__ int lab[S_];
  __shared__ float red[TPB];
  int L = slen[b];
  for (int s = t; s < S_; s += TPB){
    int lb = labels[b*S_ + s];
    lab[s] = (s < L) ? lb : -1;
  }
  __syncthreads();
  if (dz == 0 && t < 16){
    unsigned int wword = 0;
    for (int i2=0;i2<32;i2++) if (lab[t*32+i2]==1) wword |= (1u<<i2);
    wpbits[b*16+t] = wword;
  }
  int cpi=0, cni=0;
  for (int s=t; s<S_; s+=TPB){ cpi += (lab[s]==1); cni += (lab[s]==0); }
  red[t] = (float)cpi; __syncthreads();
  for (int o=TPB/2;o>0;o>>=1){ if(t<o) red[t]+=red[t+o]; __syncthreads(); }
  float cp = red[0]; __syncthreads();
  red[t] = (float)cni; __syncthreads();
  for (int o=TPB/2;o>0;o>>=1){ if(t<o) red[t]+=red[t+o]; __syncthreads(); }
  float cn = red[0];
  if (dz==0 && t==0){ cnt[b*2+0]=cn; cnt[b*2+1]=cp; }
  __syncthreads();

  int dr = t>>2, sc = (t&3)*16;
  float accp = 0.f, accn = 0.f;
  for (int sz=0; sz<8; sz++){
    int s0 = sz*64;
    const float* src = X + ((size_t)b*S_ + s0)*D_ + d0;
    { int r = t>>2, seg = (t&3)*16;
      const float4* s4 = (const float4*)(src + (size_t)r*D_ + seg);
      #pragma unroll
      for (int i=0;i<4;i++){ float4 v = s4[i];
        Tl[seg+i*4+0][r]=v.x; Tl[seg+i*4+1][r]=v.y; Tl[seg+i*4+2][r]=v.z; Tl[seg+i*4+3][r]=v.w; } }
    __syncthreads();
    union U16 { unsigned short u[8]; uint4 v; };
    U16 H[2], Lo[2];
    #pragma unroll
    for (int g=0; g<2; g++)
      #pragma unroll
      for (int i=0;i<8;i++){
        int si = sc + g*8 + i;
        float x = (s0+si < L) ? Tl[dr][si] : 0.f;
        _Float16 hh = (_Float16)x;
        float lo = x - (float)hh;
        H[g].u[i]  = __builtin_bit_cast(unsigned short, hh);
        Lo[g].u[i] = __builtin_bit_cast(unsigned short, (_Float16)lo);
      }
    size_t o = ((size_t)b*D_ + d0+dr)*S_ + s0 + sc;
    *(uint4*)(Xvh+o)   = H[0].v;  *(uint4*)(Xvh+o+8) = H[1].v;
    *(uint4*)(Xvl+o)   = Lo[0].v; *(uint4*)(Xvl+o+8) = Lo[1].v;
    #pragma unroll
    for (int i=0;i<16;i++){
      int si = sc + i;
      int e = lab[s0+si];
      float x = Tl[dr][si];
      accp += (e==1) ? x : 0.f;
      accn += (e==0) ? x : 0.f;
    }
    __syncthreads();
  }
  accp += __shfl_xor(accp, 1, 64);
  accp += __shfl_xor(accp, 2, 64);
  accn += __shfl_xor(accn, 1, 64);
  accn += __shfl_xor(accn, 2, 64);
  if ((t&3)==0){
    int d = d0 + dr;
    float stv = (float)L;
    float* mb = mu + (size_t)b*3*D_;
    mb[0*D_ + d] = accn/cn;
    mb[1*D_ + d] = accp/cp;
    mb[2*D_ + d] = (accn+accp)/stv;
  }
}

// ---------------- MFMA Gram -> A matrices (upper 128-tiles incl. diagonal) ----------------
__global__ __launch_bounds__(TPB,2) void k_gram(const unsigned short* __restrict__ Xvh,
                                                const unsigned short* __restrict__ Xvl,
                                                const unsigned int* __restrict__ wpbits,
                                                const float* __restrict__ mu,
                                                const float* __restrict__ cnt,
                                                const int* __restrict__ slen,
                                                float* __restrict__ A)
{
  __shared__ unsigned short sAvh[128][32], sAvl[128][32], sAph[128][32], sApl[128][32],
                            sBvh[128][32], sBvl[128][32];
  int id = blockIdx.x;
  int g = id>>3;
  int b = (g/10)*8 + (id&7);
  int z = g%10;
  int ti=0; while (z >= 4-ti){ z -= 4-ti; ti++; } int tj = ti + z;
  int i0 = ti*128, j0 = tj*128;
  int t = threadIdx.x, lane = t&63, w = t>>6;
  int wr = w>>1, wc = w&1, l15 = lane&15;

  f32x4 acc_t[4][4], acc_p[4][4];
  f32x4 z4 = {0.f,0.f,0.f,0.f};
  #pragma unroll
  for (int mf=0;mf<4;mf++)
    #pragma unroll
    for (int nf=0;nf<4;nf++){ acc_t[mf][nf]=z4; acc_p[mf][nf]=z4; }

  const size_t baseA = ((size_t)b*D_ + i0)*S_;
  const size_t baseB = ((size_t)b*D_ + j0)*S_;
  int phx = (lane>>4) ^ ((l15>>1)&3);

  for (int ks=0; ks<16; ks++){
    int s0 = ks*32;
    unsigned int wpw = wpbits[b*16 + ks];
    __syncthreads();
    #pragma unroll
    for (int h=0; h<2; h++){
      int ci = t + h*256;
      int row = ci>>2, cpos = ci&3;
      int ph = cpos ^ ((row>>1)&3);
      size_t ga = baseA + (size_t)row*S_ + s0 + cpos*8;
      size_t gb = baseB + (size_t)row*S_ + s0 + cpos*8;
      uint4 vh = *(const uint4*)(Xvh+ga);
      uint4 vl = *(const uint4*)(Xvl+ga);
      uint4 bh = *(const uint4*)(Xvh+gb);
      uint4 bl = *(const uint4*)(Xvl+gb);
      unsigned int m8 = (wpw >> (cpos*8)) & 0xFFu;
      uint4 mk;
      mk.x = ((m8&1u)?0xFFFFu:0u)  | ((m8&2u)?0xFFFF0000u:0u);
      mk.y = ((m8&4u)?0xFFFFu:0u)  | ((m8&8u)?0xFFFF0000u:0u);
      mk.z = ((m8&16u)?0xFFFFu:0u) | ((m8&32u)?0xFFFF0000u:0u);
      mk.w = ((m8&64u)?0xFFFFu:0u) | ((m8&128u)?0xFFFF0000u:0u);
      uint4 p4, q4;
      p4.x = vh.x&mk.x; p4.y = vh.y&mk.y; p4.z = vh.z&mk.z; p4.w = vh.w&mk.w;
      q4.x = vl.x&mk.x; q4.y = vl.y&mk.y; q4.z = vl.z&mk.z; q4.w = vl.w&mk.w;
      *(uint4*)&sAvh[row][ph*8] = vh;
      *(uint4*)&sAvl[row][ph*8] = vl;
      *(uint4*)&sAph[row][ph*8] = p4;
      *(uint4*)&sApl[row][ph*8] = q4;
      *(uint4*)&sBvh[row][ph*8] = bh;
      *(uint4*)&sBvl[row][ph*8] = bl;
    }
    __syncthreads();
    f16x8 Avh[4], Avl[4], Aph[4], Apl[4];
    #pragma unroll
    for (int mf=0;mf<4;mf++){
      int r = wr*64 + mf*16 + l15;
      Avh[mf] = __builtin_bit_cast(f16x8, *(const uint4*)&sAvh[r][phx*8]);
      Avl[mf] = __builtin_bit_cast(f16x8, *(const uint4*)&sAvl[r][phx*8]);
      Aph[mf] = __builtin_bit_cast(f16x8, *(const uint4*)&sAph[r][phx*8]);
      Apl[mf] = __builtin_bit_cast(f16x8, *(const uint4*)&sApl[r][phx*8]);
    }
    #pragma unroll
    for (int nf=0;nf<4;nf++){
      int r = wc*64 + nf*16 + l15;
      f16x8 Bh = __builtin_bit_cast(f16x8, *(const uint4*)&sBvh[r][phx*8]);
      f16x8 Bl = __builtin_bit_cast(f16x8, *(const uint4*)&sBvl[r][phx*8]);
      #pragma unroll
      for (int mf=0;mf<4;mf++){
        acc_t[mf][nf] = __builtin_amdgcn_mfma_f32_16x16x32_f16(Avh[mf], Bh, acc_t[mf][nf],0,0,0);
        acc_t[mf][nf] = __builtin_amdgcn_mfma_f32_16x16x32_f16(Avh[mf], Bl, acc_t[mf][nf],0,0,0);
        acc_t[mf][nf] = __builtin_amdgcn_mfma_f32_16x16x32_f16(Avl[mf], Bh, acc_t[mf][nf],0,0,0);
        acc_p[mf][nf] = __builtin_amdgcn_mfma_f32_16x16x32_f16(Aph[mf], Bh, acc_p[mf][nf],0,0,0);
        acc_p[mf][nf] = __builtin_amdgcn_mfma_f32_16x16x32_f16(Aph[mf], Bl, acc_p[mf][nf],0,0,0);
        acc_p[mf][nf] = __builtin_amdgcn_mfma_f32_16x16x32_f16(Apl[mf], Bh, acc_p[mf][nf],0,0,0);
      }
    }
  }
  float cn = cnt[b*2+0], cp = cnt[b*2+1];
  float stv = (float)slen[b];
  float kn = 0.1f/(cn-1.f), kp = 0.1f/(cp-1.f), kt = 0.9f/(stv-1.f);
  float rn = 0.1f*cn/(cn-1.f), rp = 0.1f*cp/(cp-1.f), rt = 0.9f*stv/(stv-1.f);
  const float* mb = mu + (size_t)b*3*D_;
  float* A0 = A + (size_t)(b*2+0)*D_*D_;
  float* A1 = A + (size_t)(b*2+1)*D_*D_;
  int rbase = i0 + wr*64 + (lane>>4)*4;
  int cbase = j0 + wc*64 + l15;
  #pragma unroll
  for (int mf=0;mf<4;mf++){
    #pragma unroll
    for (int i=0;i<4;i++){
      int r = rbase + mf*16 + i;
      float mnr = mb[r], mpr = mb[D_+r], mtr = mb[2*D_+r];
      #pragma unroll
      for (int nf=0;nf<4;nf++){
        int c = cbase + nf*16;
        float mnc = mb[c], mpc = mb[D_+c], mtc = mb[2*D_+c];
        float gp = acc_p[mf][nf][i];
        float gt = acc_t[mf][nf][i];
        float gn = gt - gp;
        float diag = (r==c)?0.1f:0.f;
        A0[(size_t)r*D_ + c] = kn*gn + kt*gt - rn*mnr*mnc - rt*mtr*mtc + diag;
        A1[(size_t)r*D_ + c] = kp*gp + kt*gt - rp*mpr*mpc - rt*mtr*mtc + diag;
      }
    }
  }
}

// ---------------- diag block Cholesky + triangular inverse (transposed out) ----------------
__global__ __launch_bounds__(TPB) void k_diag(float* __restrict__ A,
                                              float* __restrict__ invDT, int j)
{
  int m, t0; decode_mt(blockIdx.x, 1, m, t0); (void)t0;
  int t = threadIdx.x;
  __shared__ float Ld[64][65];
  __shared__ float Iv[64][65];
  float* Ab = A + (size_t)m*D_*D_ + (size_t)(j*NB)*D_ + j*NB;
  for (int l=t; l<4096; l+=TPB){ int r=l>>6, c=l&63; Ld[r][c] = Ab[(size_t)r*D_ + c]; Iv[r][c] = 0.f; }
  __syncthreads();
  for (int k=0;k<64;k++){
    if (t==0) Ld[k][k] = sqrtf(Ld[k][k]);
    __syncthreads();
    if (t>k && t<64) Ld[t][k] /= Ld[k][k];
    __syncthreads();
    for (int l=t; l<4096; l+=TPB){
      int r=l>>6, c=l&63;
      if (r>k && c>k) Ld[r][c] = fmaf(-Ld[r][k], Ld[c][k], Ld[r][c]);
    }
    __syncthreads();
  }
  if (t < 64){
    int c = t;
    Iv[c][c] = 1.f/Ld[c][c];
    for (int r=c+1;r<64;r++){
      float s = 0.f;
      for (int k2=c;k2<r;k2++) s += Ld[r][k2]*Iv[k2][c];
      Iv[r][c] = -s/Ld[r][r];
    }
  }
  __syncthreads();
  float* Ib = invDT + ((size_t)m*8 + j)*4096;
  for (int l=t; l<4096; l+=TPB){ Ib[l] = Iv[l&63][l>>6]; }
}

// ---------------- panel: upper(j,ib) <- invD * upper(j,ib); emit f16T hi/lo ----------------
__global__ __launch_bounds__(TPB) void k_panel(float* __restrict__ A,
                                               const float* __restrict__ invDT,
                                               unsigned short* __restrict__ Ut,
                                               int j, int W)
{
  int m, ti; decode_mt(blockIdx.x, W, m, ti);
  int ib = j + 1 + ti;
  int t = threadIdx.x, tr = t&15, tc = t>>4;
  __shared__ float Ta[64][68], Tb[64][68];
  float* U = A + (size_t)m*D_*D_ + (size_t)(j*NB)*D_ + ib*NB;
  stage_D(invDT + ((size_t)m*8 + j)*4096, 64, Ta, t);
  stage_D(U, D_, Tb, t);
  __syncthreads();
  float acc[4][4] = {};
  mm_acc68(Ta, Tb, acc, tr, tc);
  #pragma unroll
  for (int u=0;u<4;u++){
    float4 o = make_float4(acc[u][0],acc[u][1],acc[u][2],acc[u][3]);
    *((float4*)(U + (size_t)(tr*4+u)*D_ + tc*4)) = o;
  }
  __syncthreads();
  unsigned short* shh = (unsigned short*)Ta;
  unsigned short* shl = (unsigned short*)Tb;
  #pragma unroll
  for (int u=0;u<4;u++)
    #pragma unroll
    for (int v=0;v<4;v++){
      float val = acc[u][v];                  // P[x=tr*4+u][y=tc*4+v]
      _Float16 h = (_Float16)val;
      float lo = val - (float)h;
      shh[(tc*4+v)*72 + tr*4+u] = __builtin_bit_cast(unsigned short, h);
      shl[(tc*4+v)*72 + tr*4+u] = __builtin_bit_cast(unsigned short, (_Float16)lo);
    }
  __syncthreads();
  unsigned short* Ub = Ut + ((size_t)m*28 + pidx(j, ib)) * 8192;
  { int r = t>>2, cs = (t&3)*16;
    *(uint4*)(Ub + r*64 + cs)          = *(uint4*)&shh[r*72 + cs];
    *(uint4*)(Ub + r*64 + cs + 8)      = *(uint4*)&shh[r*72 + cs + 8];
    *(uint4*)(Ub + 4096 + r*64 + cs)   = *(uint4*)&shl[r*72 + cs];
    *(uint4*)(Ub + 4096 + r*64 + cs+8) = *(uint4*)&shl[r*72 + cs + 8];
  }
}

// ---------------- MFMA trail helpers ----------------
__device__ __forceinline__ void trail_stage(const unsigned short* __restrict__ Ua,
                                            const unsigned short* __restrict__ Ub,
                                            unsigned short (*Ah)[72], unsigned short (*Al)[72],
                                            unsigned short (*Bh)[72], unsigned short (*Bl)[72],
                                            int t)
{
  int r = t>>2, cs = (t&3)*16;
  *(uint4*)&Ah[r][cs]   = *(const uint4*)(Ua + r*64 + cs);
  *(uint4*)&Ah[r][cs+8] = *(const uint4*)(Ua + r*64 + cs + 8);
  *(uint4*)&Al[r][cs]   = *(const uint4*)(Ua + 4096 + r*64 + cs);
  *(uint4*)&Al[r][cs+8] = *(const uint4*)(Ua + 4096 + r*64 + cs + 8);
  *(uint4*)&Bh[r][cs]   = *(const uint4*)(Ub + r*64 + cs);
  *(uint4*)&Bh[r][cs+8] = *(const uint4*)(Ub + r*64 + cs + 8);
  *(uint4*)&Bl[r][cs]   = *(const uint4*)(Ub + 4096 + r*64 + cs);
  *(uint4*)&Bl[r][cs+8] = *(const uint4*)(Ub + 4096 + r*64 + cs + 8);
}

__device__ __forceinline__ void trail_mfma(const unsigned short (*Ah)[72], const unsigned short (*Al)[72],
                                           const unsigned short (*Bh)[72], const unsigned short (*Bl)[72],
                                           f32x4 acc[4], int w, int l15, int lk)
{
  #pragma unroll
  for (int s=0;s<2;s++){
    f16x8 Afh = __builtin_bit_cast(f16x8, *(const uint4*)&Ah[w*16 + l15][s*32 + lk*8]);
    f16x8 Afl = __builtin_bit_cast(f16x8, *(const uint4*)&Al[w*16 + l15][s*32 + lk*8]);
    #pragma unroll
    for (int ni=0;ni<4;ni++){
      f16x8 Bfh = __builtin_bit_cast(f16x8, *(const uint4*)&Bh[ni*16 + l15][s*32 + lk*8]);
      f16x8 Bfl = __builtin_bit_cast(f16x8, *(const uint4*)&Bl[ni*16 + l15][s*32 + lk*8]);
      acc[ni] = __builtin_amdgcn_mfma_f32_16x16x32_f16(Afh, Bfh, acc[ni],0,0,0);
      acc[ni] = __builtin_amdgcn_mfma_f32_16x16x32_f16(Afh, Bfl, acc[ni],0,0,0);
      acc[ni] = __builtin_amdgcn_mfma_f32_16x16x32_f16(Afl, Bfh, acc[ni],0,0,0);
    }
  }
}

__device__ __forceinline__ void trail_rmw(float* __restrict__ Cb, const f32x4 acc[4],
                                          int w, int l15, int lk)
{
  #pragma unroll
  for (int ni=0;ni<4;ni++)
    #pragma unroll
    for (int i=0;i<4;i++){
      int r = w*16 + lk*4 + i, cc = ni*16 + l15;
      float* pC = Cb + (size_t)r*D_ + cc;
      *pC -= acc[ni][i];
    }
}

// ---------------- trailrow (MFMA): upper(row,b) -= U(j,row)^T U(j,b) ----------------
__global__ __launch_bounds__(TPB) void k_trailrow(float* __restrict__ A,
                                                  const unsigned short* __restrict__ Ut,
                                                  int j, int row, int W)
{
  int m, z; decode_mt(blockIdx.x, W, m, z);
  int b2 = row + z;
  int t = threadIdx.x, lane = t&63, w = t>>6, l15 = lane&15, lk = lane>>4;
  __shared__ unsigned short Ah[64][72], Al[64][72], Bh[64][72], Bl[64][72];
  const unsigned short* Um = Ut + (size_t)m*28*8192;
  trail_stage(Um + (size_t)pidx(j,row)*8192, Um + (size_t)pidx(j,b2)*8192, Ah, Al, Bh, Bl, t);
  __syncthreads();
  f32x4 acc[4];
  #pragma unroll
  for (int ni=0;ni<4;ni++) acc[ni] = (f32x4){0.f,0.f,0.f,0.f};
  trail_mfma(Ah, Al, Bh, Bl, acc, w, l15, lk);
  float* Cb = A + (size_t)m*D_*D_ + (size_t)(row*NB)*D_ + b2*NB;
  trail_rmw(Cb, acc, w, l15, lk);
}

// ---------------- trail2 (MFMA): upper(a,b) -= cols jb,jb+1 ----------------
__global__ __launch_bounds__(TPB) void k_trail2(float* __restrict__ A,
                                                const unsigned short* __restrict__ Ut,
                                                int jb, int W)
{
  int m, z; decode_mt(blockIdx.x, W, m, z);
  int base = jb + 2;
  int Tn = NT - base;
  int p = 0, zz = z;
  while (zz >= Tn - p){ zz -= Tn - p; p++; }
  int a2 = base + p, b2 = a2 + zz;
  int t = threadIdx.x, lane = t&63, w = t>>6, l15 = lane&15, lk = lane>>4;
  __shared__ unsigned short Ah[64][72], Al[64][72], Bh[64][72], Bl[64][72];
  const unsigned short* Um = Ut + (size_t)m*28*8192;
  f32x4 acc[4];
  #pragma unroll
  for (int ni=0;ni<4;ni++) acc[ni] = (f32x4){0.f,0.f,0.f,0.f};
  #pragma unroll
  for (int c=0;c<2;c++){
    int j = jb + c;
    __syncthreads();
    trail_stage(Um + (size_t)pidx(j,a2)*8192, Um + (size_t)pidx(j,b2)*8192, Ah, Al, Bh, Bl, t);
    __syncthreads();
    trail_mfma(Ah, Al, Bh, Bl, acc, w, l15, lk);
  }
  float* Cb = A + (size_t)m*D_*D_ + (size_t)(a2*NB)*D_ + b2*NB;
  trail_rmw(Cb, acc, w, l15, lk);
}

// ---------------- fused rform + forward solve + maha + logits ----------------
__global__ __launch_bounds__(TPB) void k_solvefin(const float* __restrict__ Qs,
                                                  const float* __restrict__ mu,
                                                  const float* __restrict__ A,
                                                  const float* __restrict__ invDT,
                                                  float* __restrict__ Z,
                                                  const int* __restrict__ qlen,
                                                  const float* __restrict__ lps,
                                                  float* __restrict__ out)
{
  int m, t0; decode_mt(blockIdx.x, 4, m, t0);
  int q0 = t0*NB;
  int b = m>>1, cls = m&1;
  int t = threadIdx.x, tr = t&15, tc = t>>4;
  __shared__ float Ta[64][68], Tb[64][68];
  const float* Am = A + (size_t)m*D_*D_;
  float* Zm = Z + (size_t)m*D_*Q_;
  const float* muv = mu + ((size_t)b*3 + cls)*D_;
  float cs[4] = {0.f,0.f,0.f,0.f};
  for (int j=0;j<NT;j++){
    float acc[4][4];
    {
      float4 mv = *(const float4*)&muv[j*NB + tr*4];
      #pragma unroll
      for (int v=0;v<4;v++){
        float4 qv = *(const float4*)&Qs[((size_t)b*Q_ + q0 + tc*4 + v)*D_ + j*NB + tr*4];
        acc[0][v] = mv.x - qv.x;
        acc[1][v] = mv.y - qv.y;
        acc[2][v] = mv.z - qv.z;
        acc[3][v] = mv.w - qv.w;
      }
    }
    for (int k=0;k<j;k++){
      stage_D(Am + (size_t)(k*NB)*D_ + j*NB, D_, Ta, t);
      { int r = t >> 2, seg = (t & 3)*16;
        const float4* s4 = (const float4*)(Zm + (size_t)(k*NB + r)*Q_ + q0 + seg);
        #pragma unroll
        for (int i=0;i<4;i++) *((float4*)&Tb[r][seg + i*4]) = s4[i];
      }
      __syncthreads();
      for (int kk=0;kk<64;kk++){
        float4 av = *((const float4*)&Ta[kk][tr*4]);
        float4 bv = *((const float4*)&Tb[kk][tc*4]);
        float a[4]={av.x,av.y,av.z,av.w}, bb2[4]={bv.x,bv.y,bv.z,bv.w};
        #pragma unroll
        for (int u=0;u<4;u++)
          #pragma unroll
          for (int v=0;v<4;v++) acc[u][v] = fmaf(-a[u], bb2[v], acc[u][v]);
      }
      __syncthreads();
    }
    // S -> Tb with XOR granule swizzle (kills 8-way scatter conflict)
    #pragma unroll
    for (int u=0;u<4;u++){
      int cb = (tc*4) ^ ((tr&7)<<2);
      *((float4*)&Tb[tr*4+u][cb]) = make_float4(acc[u][0],acc[u][1],acc[u][2],acc[u][3]);
    }
    stage_D(invDT + ((size_t)m*8 + j)*4096, 64, Ta, t);
    __syncthreads();
    float o4[4][4] = {};
    for (int kk=0;kk<64;kk++){
      float4 av = *((const float4*)&Ta[kk][tr*4]);
      float4 bv = *((const float4*)&Tb[kk][(tc*4) ^ (((kk>>2)&7)<<2)]);
      float a[4]={av.x,av.y,av.z,av.w}, bb2[4]={bv.x,bv.y,bv.z,bv.w};
      #pragma unroll
      for (int u=0;u<4;u++)
        #pragma unroll
        for (int v=0;v<4;v++) o4[u][v] = fmaf(a[u], bb2[v], o4[u][v]);
    }
    if (j < NT-1){
      #pragma unroll
      for (int u=0;u<4;u++){
        float4 o = make_float4(o4[u][0], o4[u][1], o4[u][2], o4[u][3]);
        *((float4*)(Zm + (size_t)(j*NB + tr*4+u)*Q_ + q0 + tc*4)) = o;
      }
    }
    #pragma unroll
    for (int u=0;u<4;u++)
      #pragma unroll
      for (int v=0;v<4;v++) cs[v] = fmaf(o4[u][v], o4[u][v], cs[v]);
    __syncthreads();
  }
  float* red = &Ta[0][0];
  #pragma unroll
  for (int v=0;v<4;v++) red[(tc*4+v)*16 + tr] = cs[v];
  __syncthreads();
  if (t < 64){
    float s = 0.f;
    #pragma unroll
    for (int i=0;i<16;i++) s += red[t*16 + i];
    int q = q0 + t;
    float valid = (q < qlen[b]) ? 1.f : 0.f;
    float s2 = expf(2.f*lps[0]);
    out[((size_t)b*Q_ + q)*2 + cls] = -s2*s*valid;
  }
}

extern "C" void kernel_launch(void* const* d_in, const int* in_sizes, int n_in,
                              void* d_out, int out_size, void* d_ws, size_t ws_size,
                              hipStream_t stream) {
  (void)in_sizes; (void)n_in; (void)out_size;
  const float* X   = (const float*)d_in[0];
  const int*   lab = (const int*)d_in[1];
  const float* Qs  = (const float*)d_in[2];
  const int*   sl  = (const int*)d_in[3];
  const int*   ql  = (const int*)d_in[4];
  const float* lps = (const float*)d_in[5];
  float* out = (float*)d_out;

  float* A  = (float*)d_ws;                          // [512,512,512] f32
  float* Z  = A + (size_t)NM_*D_*D_;                 // [512,512,256] f32
  unsigned short* Xvh = (unsigned short*)Z;          // overlays Z (gram phase only)
  unsigned short* Xvl = Xvh + (size_t)B_*D_*S_;
  unsigned short* Ut  = (unsigned short*)Z;          // overlays Z (chol phase only): [512][28][8192]
  float* invDT = Z + (size_t)NM_*D_*Q_;              // [512,8,64,64] f32 (transposed)
  float* mu   = invDT + (size_t)NM_*8*64*64;         // [256,3,512]
  float* cnt  = mu + (size_t)B_*3*D_;                // [256,2]
  unsigned int* wpbits = (unsigned int*)(cnt + B_*2);// [256,16]
  size_t need = (size_t)((char*)(wpbits + B_*16) - (char*)d_ws);
  if (ws_size < need) return;

  k_prep<<<dim3(8, B_), dim3(TPB), 0, stream>>>(X, lab, sl, Xvh, Xvl, mu, cnt, wpbits);
  k_gram<<<dim3(2560), dim3(TPB), 0, stream>>>(Xvh, Xvl, wpbits, mu, cnt, sl, A);

  // lazy two-column Cholesky with MFMA trail (f16T panels live in the Z region)
  for (int j=0; j<NT; j+=2){
    k_diag<<<dim3(NM_), dim3(TPB), 0, stream>>>(A, invDT, j);
    int nb0 = NT-1-j;
    if (nb0 > 0){
      k_panel<<<dim3(NM_*nb0), dim3(TPB), 0, stream>>>(A, invDT, Ut, j, nb0);
      int wr = NT - (j+1);
      k_trailrow<<<dim3(NM_*wr), dim3(TPB), 0, stream>>>(A, Ut, j, j+1, wr);
      k_diag<<<dim3(NM_), dim3(TPB), 0, stream>>>(A, invDT, j+1);
      int nb1 = NT-1-(j+1);
      if (nb1 > 0){
        k_panel<<<dim3(NM_*nb1), dim3(TPB), 0, stream>>>(A, invDT, Ut, j+1, nb1);
        int Tn = NT - (j+2);
        int np = Tn*(Tn+1)/2;
        if (np > 0) k_trail2<<<dim3(NM_*np), dim3(TPB), 0, stream>>>(A, Ut, j, np);
      }
    }
  }

  k_solvefin<<<dim3(NM_*4), dim3(TPB), 0, stream>>>(Qs, mu, A, invDT, Z, ql, lps, out);
}